// Round 3
// baseline (491.080 us; speedup 1.0000x reference)
//
#include <hip/hip_runtime.h>
#include <math.h>

#define B_  256
#define IU  8
#define IC  1152
#define NU  10
#define US  16
#define ROWS 2048   // B_*IU
#define CCH 9
#define NCH 128
#define BT  64
#define NBLK 512

// ---------------- x transpose: x[b][i][c] -> xT[c][b*8+i] ----------------
__global__ __launch_bounds__(256) void transpose_x(const float* __restrict__ x,
                                                   float* __restrict__ xT) {
    __shared__ float t[32][33];
    const int tx = threadIdx.x & 31, ty = threadIdx.x >> 5;
    const int ct = blockIdx.x % 36;
    const int rt = blockIdx.x / 36;
    const int c0 = ct * 32, r0 = rt * 32;
#pragma unroll
    for (int k = 0; k < 32; k += 8)
        t[ty + k][tx] = x[(size_t)(r0 + ty + k) * IC + c0 + tx];
    __syncthreads();
#pragma unroll
    for (int k = 0; k < 32; k += 8)
        xT[(size_t)(c0 + ty + k) * ROWS + r0 + tx] = t[tx][ty + k];
}

// ---------------- two-level grid barrier (requires all 512 blocks resident;
// guaranteed: 65 KB LDS/block => exactly 2 blocks/CU x 256 CU) ----------------
__device__ __forceinline__ void gridbar(unsigned* bar, int grp) {
    __syncthreads();
    if (threadIdx.x == 0) {
        __threadfence();
        unsigned* gen = bar + 144;
        unsigned g = __hip_atomic_load(gen, __ATOMIC_RELAXED, __HIP_MEMORY_SCOPE_AGENT);
        unsigned a = __hip_atomic_fetch_add(bar + grp * 16, 1u, __ATOMIC_ACQ_REL,
                                            __HIP_MEMORY_SCOPE_AGENT);
        if (a == (NBLK / 8 - 1)) {   // last block of this group
            __hip_atomic_store(bar + grp * 16, 0u, __ATOMIC_RELAXED, __HIP_MEMORY_SCOPE_AGENT);
            unsigned r = __hip_atomic_fetch_add(bar + 128, 1u, __ATOMIC_ACQ_REL,
                                                __HIP_MEMORY_SCOPE_AGENT);
            if (r == 7u) {           // last group: release
                __hip_atomic_store(bar + 128, 0u, __ATOMIC_RELAXED, __HIP_MEMORY_SCOPE_AGENT);
                __hip_atomic_store(gen, g + 1u, __ATOMIC_RELEASE, __HIP_MEMORY_SCOPE_AGENT);
            } else {
                while (__hip_atomic_load(gen, __ATOMIC_RELAXED, __HIP_MEMORY_SCOPE_AGENT) == g)
                    __builtin_amdgcn_s_sleep(2);
            }
        } else {
            while (__hip_atomic_load(gen, __ATOMIC_RELAXED, __HIP_MEMORY_SCOPE_AGENT) == g)
                __builtin_amdgcn_s_sleep(2);
        }
        __threadfence();
    }
    __syncthreads();
}

// ---------------- persistent routing kernel ----------------
// Block = (c-chunk ch of 9 channels, b-tile bt of 64 batches). W+x staged in LDS ONCE,
// reused across 3 s-phases and 2 agree-phases. Phases separated by gridbar.
__global__ __launch_bounds__(256, 2) void mega(const float* __restrict__ xT,
                                               const float* __restrict__ W,
                                               float* __restrict__ sp,
                                               float* __restrict__ vbuf,
                                               float* __restrict__ ap,
                                               float* __restrict__ cT,
                                               float* __restrict__ out,
                                               unsigned* __restrict__ bar) {
    __shared__ float4 ws[CCH * NU * 2 * 16];            // 46080 B raw W [cc][d][h][uq]
    __shared__ __align__(16) float xs[CCH * BT * IU];   // 18432 B  [cc][bl][i]
    __shared__ float scratch[168];                      // cs(90)/smag(160)/red — phase-local

    const int tid = threadIdx.x;
    const int bid = blockIdx.x;
    const int grp = bid & 7;                 // XCD group (also barrier group)
    const int slot = bid >> 3;
    const int ch = ((slot >> 2) << 3) | grp; // chunk pinned to one XCD
    const int bt = slot & 3;
    const int b0 = bt * BT, c0 = ch * CCH;

    // ---- one-time staging ----
    const float4* wg = (const float4*)W + (size_t)c0 * 320;
    for (int q = tid; q < CCH * NU * 32; q += 256) {
        int h = q & 1, u = (q >> 1) & 15, cd = q >> 5;
        ws[(cd * 2 + h) * 16 + u] = wg[q];
    }
    const float4* xg = (const float4*)xT;
    float4* xsv = (float4*)xs;
    for (int q = tid; q < CCH * BT * 2; q += 256) {
        int cc = q >> 7, r = q & 127;
        xsv[cc * 128 + r] = xg[(size_t)(c0 + cc) * (ROWS / 4) + b0 * 2 + r];
    }

    const int uq = tid & 15;
    const int bs = tid >> 4;
    float bn[5] = {0.f, 0.f, 0.f, 0.f, 0.f};   // b_ij in regs (bsm blocks only)

    for (int iter = 0; iter < 3; ++iter) {
        // ---- stage c_ij slice into scratch ----
        __syncthreads();
        if (iter == 0) {
            for (int q = tid; q < NU * CCH; q += 256) scratch[q] = 1.0f;
        } else {
            for (int q = tid; q < NU * CCH; q += 256) {
                int d = q / CCH, cc = q - d * CCH;
                scratch[q] = cT[d * IC + c0 + cc];
            }
        }
        __syncthreads();
        const float scale = iter ? 1.0f : (1.0f / (float)IC);   // softmax(0) uniform

        // ---- s phase: thread (uq, bs) x 4 bb, all 10 d ----
        {
            float acc[4][NU];
#pragma unroll
            for (int bb = 0; bb < 4; bb++)
#pragma unroll
                for (int d = 0; d < NU; d++) acc[bb][d] = 0.0f;

#pragma unroll 3
            for (int cc = 0; cc < CCH; cc++) {
                float4 xv0[4], xv1[4];
#pragma unroll
                for (int bb = 0; bb < 4; bb++) {
                    const float4* xp = (const float4*)(xs + (cc * BT + bs + 16 * bb) * IU);
                    xv0[bb] = xp[0]; xv1[bb] = xp[1];
                }
#pragma unroll
                for (int d = 0; d < NU; d++) {
                    float4 w0 = ws[((cc * NU + d) * 2 + 0) * 16 + uq];
                    float4 w1 = ws[((cc * NU + d) * 2 + 1) * 16 + uq];
                    const float cw = scratch[d * CCH + cc];
#pragma unroll
                    for (int bb = 0; bb < 4; bb++) {
                        float uh = w0.x * xv0[bb].x + w0.y * xv0[bb].y + w0.z * xv0[bb].z + w0.w * xv0[bb].w
                                 + w1.x * xv1[bb].x + w1.y * xv1[bb].y + w1.z * xv1[bb].z + w1.w * xv1[bb].w;
                        acc[bb][d] = fmaf(cw, uh, acc[bb][d]);
                    }
                }
            }
#pragma unroll
            for (int bb = 0; bb < 4; bb++) {
                const int b = b0 + bs + 16 * bb;
#pragma unroll
                for (int d = 0; d < NU; d++)
                    sp[(((size_t)ch * B_ + b) * NU + d) * US + uq] = acc[bb][d] * scale;
            }
        }
        gridbar(bar, grp);

        // ---- squash: blocks 0..255, one batch each ----
        if (bid < B_) {
            const int d = tid >> 4;
            float s = 0.0f;
            if (tid < NU * US) {
#pragma unroll 8
                for (int chp = 0; chp < NCH; chp++)
                    s += sp[(((size_t)chp * B_ + bid) * NU + d) * US + uq];
                scratch[tid] = s * s;
            }
            __syncthreads();
            if (tid < NU * US) {
                float msq = 0.0f;
#pragma unroll
                for (int dd = 0; dd < NU; dd++) msq += scratch[dd * US + uq];
                float f = msq / ((1.0f + msq) * sqrtf(msq));
                float* dst = (iter == 2) ? out : vbuf;
                dst[((size_t)bid * NU + d) * US + uq] = s * f;
            }
        }
        if (iter == 2) return;
        gridbar(bar, grp);

        // ---- agree phase: thread (uq, cl<9); W from LDS into regs, 64 b streamed ----
        {
            const int cl = tid >> 4;
            if (cl < CCH) {
                float4 wA[NU], wB[NU];
#pragma unroll
                for (int d = 0; d < NU; d++) {
                    wA[d] = ws[((cl * NU + d) * 2 + 0) * 16 + uq];
                    wB[d] = ws[((cl * NU + d) * 2 + 1) * 16 + uq];
                }
                float accd[NU];
#pragma unroll
                for (int d = 0; d < NU; d++) accd[d] = 0.0f;
                const int bstag = (cl & 3) * 7;   // de-conflict x-reads across cl lanes
#pragma unroll 4
                for (int blx = 0; blx < BT; blx++) {
                    const int bl = (blx + bstag) & 63;
                    const float* xp = xs + (cl * BT + bl) * IU;
                    float4 x0 = *(const float4*)xp;
                    float4 x1 = *(const float4*)(xp + 4);
                    const float* vp = vbuf + (size_t)(b0 + bl) * NU * US + uq;
#pragma unroll
                    for (int d = 0; d < NU; d++) {
                        float uh = wA[d].x * x0.x + wA[d].y * x0.y + wA[d].z * x0.z + wA[d].w * x0.w
                                 + wB[d].x * x1.x + wB[d].y * x1.y + wB[d].z * x1.z + wB[d].w * x1.w;
                        accd[d] = fmaf(uh, vp[d * US], accd[d]);
                    }
                }
#pragma unroll
                for (int d = 0; d < NU; d++) {
                    float a = accd[d];
                    a += __shfl_xor(a, 1, 64);
                    a += __shfl_xor(a, 2, 64);
                    a += __shfl_xor(a, 4, 64);
                    a += __shfl_xor(a, 8, 64);
                    if (uq == 0) ap[((size_t)bt * NU + d) * IC + c0 + cl] = a;
                }
            }
        }
        gridbar(bar, grp);

        // ---- bsm: blocks 0..9, b-update (in regs) + softmax over channels ----
        if (bid < NU) {
            const int d = bid;
            float lmax = -1e30f;
#pragma unroll
            for (int k = 0; k < 5; k++) {
                int c = tid + k * 256;
                if (c < IC) {
                    float a = 0.0f;
#pragma unroll
                    for (int g = 0; g < 4; g++) a += ap[((size_t)g * NU + d) * IC + c];
                    bn[k] += a * (1.0f / (float)B_);
                    lmax = fmaxf(lmax, bn[k]);
                }
            }
            for (int off = 32; off > 0; off >>= 1) lmax = fmaxf(lmax, __shfl_down(lmax, off, 64));
            const int wid = tid >> 6, lane = tid & 63;
            if (lane == 0) scratch[wid] = lmax;
            __syncthreads();
            if (tid == 0)
                scratch[8] = fmaxf(fmaxf(scratch[0], scratch[1]), fmaxf(scratch[2], scratch[3]));
            __syncthreads();
            const float mx = scratch[8];
            float e[5];
            float lsum = 0.0f;
#pragma unroll
            for (int k = 0; k < 5; k++) {
                int c = tid + k * 256;
                if (c < IC) { e[k] = expf(bn[k] - mx); lsum += e[k]; }
            }
            for (int off = 32; off > 0; off >>= 1) lsum += __shfl_down(lsum, off, 64);
            if (lane == 0) scratch[wid] = lsum;
            __syncthreads();
            if (tid == 0) scratch[8] = 1.0f / (scratch[0] + scratch[1] + scratch[2] + scratch[3]);
            __syncthreads();
            const float inv = scratch[8];
#pragma unroll
            for (int k = 0; k < 5; k++) {
                int c = tid + k * 256;
                if (c < IC) cT[d * IC + c] = e[k] * inv;
            }
        }
        gridbar(bar, grp);
    }
}

extern "C" void kernel_launch(void* const* d_in, const int* in_sizes, int n_in,
                              void* d_out, int out_size, void* d_ws, size_t ws_size,
                              hipStream_t stream) {
    (void)in_sizes; (void)n_in; (void)out_size; (void)ws_size;
    const float* x = (const float*)d_in[0];   // [256, 8, 1152]
    const float* W = (const float*)d_in[1];   // [1, 1152, 10, 16, 8]
    float* out = (float*)d_out;               // [256, 10, 16] fp32

    // workspace layout: bar (1 KB) | xT | sp | v | cT | ap   (~29.4 MiB total)
    unsigned* bar = (unsigned*)d_ws;
    float* xT  = (float*)d_ws + 256;
    float* sp  = xT + (size_t)IC * ROWS;             // 128*256*160
    float* v   = sp + (size_t)NCH * B_ * NU * US;    // 40,960
    float* cTb = v + (size_t)B_ * NU * US;           // 11,520
    float* apg = cTb + (size_t)NU * IC;              // 4*10*1152

    hipMemsetAsync(d_ws, 0, 1024, stream);           // barrier state
    transpose_x<<<36 * 64, 256, 0, stream>>>(x, xT);
    mega<<<NBLK, 256, 0, stream>>>(xT, W, sp, v, apg, cTb, out, bar);
}

// Round 4
// 355.394 us; speedup vs baseline: 1.3818x; 1.3818x over previous
//
#include <hip/hip_runtime.h>
#include <math.h>

#define B_  256
#define IU  8
#define IC  1152
#define NU  10
#define US  16
#define ROWS 2048   // B_*IU
#define CCH 9
#define NCH 128
#define BT  64
#define NBLK 512

// ---------------- x transpose: x[b][i][c] -> xT[c][b*8+i] ----------------
__global__ __launch_bounds__(256) void transpose_x(const float* __restrict__ x,
                                                   float* __restrict__ xT) {
    __shared__ float t[32][33];
    const int tx = threadIdx.x & 31, ty = threadIdx.x >> 5;
    const int ct = blockIdx.x % 36;
    const int rt = blockIdx.x / 36;
    const int c0 = ct * 32, r0 = rt * 32;
#pragma unroll
    for (int k = 0; k < 32; k += 8)
        t[ty + k][tx] = x[(size_t)(r0 + ty + k) * IC + c0 + tx];
    __syncthreads();
#pragma unroll
    for (int k = 0; k < 32; k += 8)
        xT[(size_t)(c0 + ty + k) * ROWS + r0 + tx] = t[tx][ty + k];
}

// ---------------- grid barrier v2 ----------------
// 3-level arrival tree (8x8x8) on padded cachelines; 8 distributed release lines
// (64 pollers each) polled with s_sleep(32) backoff. Data visibility across the
// non-coherent per-XCD L2s via __threadfence (wb before arrive, inv after release).
// bar layout (uint32 idx): L1[g]=g*32 (g<64) | L2[h]=2048+h*32 (h<8) | L3=2560
//                          gen[k]=2816+k*32 (k<8); total 3072 uints.
__device__ __forceinline__ void gridbar(unsigned* bar) {
    __syncthreads();
    if (threadIdx.x == 0) {
        __threadfence();                       // release our writes to coherence point
        const int bid = blockIdx.x;
        unsigned* genp = bar + 2816 + (bid & 7) * 32;
        unsigned g = __hip_atomic_load(genp, __ATOMIC_RELAXED, __HIP_MEMORY_SCOPE_AGENT);
        unsigned a = __hip_atomic_fetch_add(bar + (bid >> 3) * 32, 1u,
                                            __ATOMIC_RELAXED, __HIP_MEMORY_SCOPE_AGENT);
        if (a == 7u) {
            __hip_atomic_store(bar + (bid >> 3) * 32, 0u, __ATOMIC_RELAXED,
                               __HIP_MEMORY_SCOPE_AGENT);
            unsigned b2 = __hip_atomic_fetch_add(bar + 2048 + ((bid >> 6) & 7) * 32, 1u,
                                                 __ATOMIC_RELAXED, __HIP_MEMORY_SCOPE_AGENT);
            if (b2 == 7u) {
                __hip_atomic_store(bar + 2048 + ((bid >> 6) & 7) * 32, 0u,
                                   __ATOMIC_RELAXED, __HIP_MEMORY_SCOPE_AGENT);
                unsigned c2 = __hip_atomic_fetch_add(bar + 2560, 1u,
                                                     __ATOMIC_RELAXED, __HIP_MEMORY_SCOPE_AGENT);
                if (c2 == 7u) {
                    __hip_atomic_store(bar + 2560, 0u, __ATOMIC_RELAXED,
                                       __HIP_MEMORY_SCOPE_AGENT);
#pragma unroll
                    for (int k = 0; k < 8; k++)
                        __hip_atomic_store(bar + 2816 + k * 32, g + 1u,
                                           __ATOMIC_RELAXED, __HIP_MEMORY_SCOPE_AGENT);
                }
            }
        }
        while (__hip_atomic_load(genp, __ATOMIC_RELAXED, __HIP_MEMORY_SCOPE_AGENT) == g)
            __builtin_amdgcn_s_sleep(32);      // ~2k cycles/poll: 64 pollers/line is cheap
        __threadfence();                       // acquire: invalidate L2, see others' data
    }
    __syncthreads();
}

// ---------------- persistent routing kernel v2 ----------------
// Block = (c-chunk of 9 channels, b-tile of 64). W+x staged in LDS once, reused by
// 3 s-phases + 2 agree-phases. agree atomicAdds straight into b_ij; each block
// computes its own softmax slice (no bsm phase). 7 grid barriers total.
__global__ __launch_bounds__(256, 2) void mega(const float* __restrict__ xT,
                                               const float* __restrict__ W,
                                               float* __restrict__ sp,
                                               float* __restrict__ vbuf,
                                               float* __restrict__ bij,
                                               float* __restrict__ out,
                                               unsigned* __restrict__ bar) {
    __shared__ float4 ws[CCH * NU * 2 * 16];            // 46080 B raw W [cc][d][h][uq]
    __shared__ __align__(16) float xs[CCH * BT * IU];   // 18432 B  [cc][bl][i]
    __shared__ float aux[NU * US];                      // 640 B (squash smag)
    __shared__ float cs[NU * CCH];                      // 360 B (c_ij slice)

    const int tid = threadIdx.x;
    const int bid = blockIdx.x;
    const int grp = bid & 7;
    const int slot = bid >> 3;
    const int ch = ((slot >> 2) << 3) | grp;   // chunk pinned to one XCD
    const int bt = slot & 3;
    const int b0 = bt * BT, c0 = ch * CCH;

    // ---- one-time staging ----
    const float4* wg = (const float4*)W + (size_t)c0 * 320;
    for (int q = tid; q < CCH * NU * 32; q += 256) {
        int h = q & 1, u = (q >> 1) & 15, cd = q >> 5;
        ws[(cd * 2 + h) * 16 + u] = wg[q];
    }
    const float4* xg = (const float4*)xT;
    float4* xsv = (float4*)xs;
    for (int q = tid; q < CCH * BT * 2; q += 256) {
        int cc = q >> 7, r = q & 127;
        xsv[cc * 128 + r] = xg[(size_t)(c0 + cc) * (ROWS / 4) + b0 * 2 + r];
    }

    const int uq = tid & 15;
    const int bs = tid >> 4;
    const int wv = tid >> 6;      // wave id 0..3
    const int lane = tid & 63;

    for (int iter = 0; iter < 3; ++iter) {
        // ---- c_ij slice: uniform (iter 0) or per-block softmax of b_ij rows ----
        __syncthreads();
        if (iter == 0) {
            for (int q = tid; q < NU * CCH; q += 256) cs[q] = 1.0f;
        } else {
            // wave wv handles d = wv, wv+4, wv+8; full row reduction in-wave
            for (int d = wv; d < NU; d += 4) {
                const float* brow = bij + (size_t)d * IC;
                float bv[18];
                float mx = -1e30f;
#pragma unroll
                for (int j = 0; j < 18; j++) {
                    bv[j] = brow[lane + j * 64];
                    mx = fmaxf(mx, bv[j]);
                }
#pragma unroll
                for (int off = 32; off > 0; off >>= 1)
                    mx = fmaxf(mx, __shfl_xor(mx, off, 64));
                float sume = 0.0f;
#pragma unroll
                for (int j = 0; j < 18; j++) sume += expf(bv[j] - mx);
#pragma unroll
                for (int off = 32; off > 0; off >>= 1)
                    sume += __shfl_xor(sume, off, 64);
                const float inv = 1.0f / sume;
                if (lane < CCH)
                    cs[d * CCH + lane] = expf(brow[c0 + lane] - mx) * inv;
            }
        }
        __syncthreads();
        const float scale = iter ? 1.0f : (1.0f / (float)IC);   // softmax(0) uniform

        // ---- s phase ----
        {
            float acc[4][NU];
#pragma unroll
            for (int bb = 0; bb < 4; bb++)
#pragma unroll
                for (int d = 0; d < NU; d++) acc[bb][d] = 0.0f;

#pragma unroll 3
            for (int cc = 0; cc < CCH; cc++) {
                float4 xv0[4], xv1[4];
#pragma unroll
                for (int bb = 0; bb < 4; bb++) {
                    const float4* xp = (const float4*)(xs + (cc * BT + bs + 16 * bb) * IU);
                    xv0[bb] = xp[0]; xv1[bb] = xp[1];
                }
#pragma unroll
                for (int d = 0; d < NU; d++) {
                    float4 w0 = ws[((cc * NU + d) * 2 + 0) * 16 + uq];
                    float4 w1 = ws[((cc * NU + d) * 2 + 1) * 16 + uq];
                    const float cw = cs[d * CCH + cc];
#pragma unroll
                    for (int bb = 0; bb < 4; bb++) {
                        float uh = w0.x * xv0[bb].x + w0.y * xv0[bb].y + w0.z * xv0[bb].z + w0.w * xv0[bb].w
                                 + w1.x * xv1[bb].x + w1.y * xv1[bb].y + w1.z * xv1[bb].z + w1.w * xv1[bb].w;
                        acc[bb][d] = fmaf(cw, uh, acc[bb][d]);
                    }
                }
            }
#pragma unroll
            for (int bb = 0; bb < 4; bb++) {
                const int b = b0 + bs + 16 * bb;
#pragma unroll
                for (int d = 0; d < NU; d++)
                    sp[(((size_t)ch * B_ + b) * NU + d) * US + uq] = acc[bb][d] * scale;
            }
        }
        gridbar(bar);

        // ---- squash: blocks 0..255, one batch each ----
        if (bid < B_) {
            float s = 0.0f;
            if (tid < NU * US) {
#pragma unroll 8
                for (int chp = 0; chp < NCH; chp++)
                    s += sp[((size_t)chp * B_ + bid) * (NU * US) + tid];
                aux[tid] = s * s;
            }
            __syncthreads();
            if (tid < NU * US) {
                float msq = 0.0f;
#pragma unroll
                for (int dd = 0; dd < NU; dd++) msq += aux[dd * US + uq];
                float f = msq / ((1.0f + msq) * sqrtf(msq));
                float* dst = (iter == 2) ? out : vbuf;
                dst[(size_t)bid * (NU * US) + tid] = s * f;
            }
        }
        if (iter == 2) return;
        gridbar(bar);

        // ---- agree phase: thread (uq, cl<9); W from LDS regs, 64 b streamed;
        //      partial dots atomically accumulated into b_ij (pre-softmax logits) ----
        {
            const int cl = tid >> 4;
            if (cl < CCH) {
                float4 wA[NU], wB[NU];
#pragma unroll
                for (int d = 0; d < NU; d++) {
                    wA[d] = ws[((cl * NU + d) * 2 + 0) * 16 + uq];
                    wB[d] = ws[((cl * NU + d) * 2 + 1) * 16 + uq];
                }
                float accd[NU];
#pragma unroll
                for (int d = 0; d < NU; d++) accd[d] = 0.0f;
                const int bstag = (cl & 3) * 7;   // de-conflict x-reads across cl
#pragma unroll 4
                for (int blx = 0; blx < BT; blx++) {
                    const int bl = (blx + bstag) & 63;
                    const float* xp = xs + (cl * BT + bl) * IU;
                    float4 x0 = *(const float4*)xp;
                    float4 x1 = *(const float4*)(xp + 4);
                    const float* vp = vbuf + (size_t)(b0 + bl) * (NU * US) + uq;
#pragma unroll
                    for (int d = 0; d < NU; d++) {
                        float uh = wA[d].x * x0.x + wA[d].y * x0.y + wA[d].z * x0.z + wA[d].w * x0.w
                                 + wB[d].x * x1.x + wB[d].y * x1.y + wB[d].z * x1.z + wB[d].w * x1.w;
                        accd[d] = fmaf(uh, vp[d * US], accd[d]);
                    }
                }
#pragma unroll
                for (int d = 0; d < NU; d++) {
                    float a = accd[d];
                    a += __shfl_xor(a, 1, 64);
                    a += __shfl_xor(a, 2, 64);
                    a += __shfl_xor(a, 4, 64);
                    a += __shfl_xor(a, 8, 64);
                    if (uq == 0)
                        atomicAdd(bij + (size_t)d * IC + c0 + cl, a * (1.0f / (float)B_));
                }
            }
        }
        gridbar(bar);
    }
}

extern "C" void kernel_launch(void* const* d_in, const int* in_sizes, int n_in,
                              void* d_out, int out_size, void* d_ws, size_t ws_size,
                              hipStream_t stream) {
    (void)in_sizes; (void)n_in; (void)out_size; (void)ws_size;
    const float* x = (const float*)d_in[0];   // [256, 8, 1152]
    const float* W = (const float*)d_in[1];   // [1, 1152, 10, 16, 8]
    float* out = (float*)d_out;               // [256, 10, 16] fp32

    // workspace: bar (3072 u32) | bij (11520 f, zeroed) | xT | sp | vbuf  (~30 MiB)
    unsigned* bar = (unsigned*)d_ws;
    float* bij = (float*)d_ws + 3072;
    float* xT  = bij + (size_t)NU * IC;
    float* sp  = xT + (size_t)IC * ROWS;
    float* vbuf = sp + (size_t)NCH * B_ * NU * US;

    hipMemsetAsync(d_ws, 0, 3072 * 4 + (size_t)NU * IC * 4, stream);  // bar + bij
    transpose_x<<<36 * 64, 256, 0, stream>>>(x, xT);
    mega<<<NBLK, 256, 0, stream>>>(xT, W, sp, vbuf, bij, out, bar);
}

// Round 5
// 275.090 us; speedup vs baseline: 1.7852x; 1.2919x over previous
//
#include <hip/hip_runtime.h>
#include <math.h>

#define B_  256
#define IU  8
#define IC  1152
#define NU  10
#define US  16
#define ROWS 2048   // B_*IU
#define CCH 9
#define NCH 128
#define BT  64
#define NBLK 512

// write-through / cache-bypassing accessors: all cross-block data lives at the
// L3 coherence point. No buffer_wbl2 / buffer_inv anywhere in this kernel.
__device__ __forceinline__ float gld(const float* p) {
    return __hip_atomic_load(p, __ATOMIC_RELAXED, __HIP_MEMORY_SCOPE_AGENT);
}
__device__ __forceinline__ void gst(float* p, float v) {
    __hip_atomic_store(p, v, __ATOMIC_RELAXED, __HIP_MEMORY_SCOPE_AGENT);
}

// ---------------- x transpose: x[b][i][c] -> xT[c][b*8+i] ----------------
__global__ __launch_bounds__(256) void transpose_x(const float* __restrict__ x,
                                                   float* __restrict__ xT) {
    __shared__ float t[32][33];
    const int tx = threadIdx.x & 31, ty = threadIdx.x >> 5;
    const int ct = blockIdx.x % 36;
    const int rt = blockIdx.x / 36;
    const int c0 = ct * 32, r0 = rt * 32;
#pragma unroll
    for (int k = 0; k < 32; k += 8)
        t[ty + k][tx] = x[(size_t)(r0 + ty + k) * IC + c0 + tx];
    __syncthreads();
#pragma unroll
    for (int k = 0; k < 32; k += 8)
        xT[(size_t)(c0 + ty + k) * ROWS + r0 + tx] = t[tx][ty + k];
}

// ---------------- grid barrier v3: fence-free ----------------
// 3-level arrival tree (8x8x8) on padded cachelines + 8 distributed release lines.
// All shared data is write-through (gst) and read L3-direct (gld), so NO cache
// maintenance is needed: __syncthreads() drains each wave's stores (vmcnt 0)
// before the arrival RMW; release observation orders L3-direct reads after them.
__device__ __forceinline__ void gridbar(unsigned* bar) {
    __syncthreads();
    if (threadIdx.x == 0) {
        const int bid = blockIdx.x;
        unsigned* genp = bar + 2816 + (bid & 7) * 32;
        unsigned g = __hip_atomic_load(genp, __ATOMIC_RELAXED, __HIP_MEMORY_SCOPE_AGENT);
        unsigned a = __hip_atomic_fetch_add(bar + (bid >> 3) * 32, 1u,
                                            __ATOMIC_RELAXED, __HIP_MEMORY_SCOPE_AGENT);
        if (a == 7u) {
            __hip_atomic_store(bar + (bid >> 3) * 32, 0u, __ATOMIC_RELAXED,
                               __HIP_MEMORY_SCOPE_AGENT);
            unsigned b2 = __hip_atomic_fetch_add(bar + 2048 + ((bid >> 6) & 7) * 32, 1u,
                                                 __ATOMIC_RELAXED, __HIP_MEMORY_SCOPE_AGENT);
            if (b2 == 7u) {
                __hip_atomic_store(bar + 2048 + ((bid >> 6) & 7) * 32, 0u,
                                   __ATOMIC_RELAXED, __HIP_MEMORY_SCOPE_AGENT);
                unsigned c2 = __hip_atomic_fetch_add(bar + 2560, 1u,
                                                     __ATOMIC_RELAXED, __HIP_MEMORY_SCOPE_AGENT);
                if (c2 == 7u) {
                    __hip_atomic_store(bar + 2560, 0u, __ATOMIC_RELAXED,
                                       __HIP_MEMORY_SCOPE_AGENT);
#pragma unroll
                    for (int k = 0; k < 8; k++)
                        __hip_atomic_store(bar + 2816 + k * 32, g + 1u,
                                           __ATOMIC_RELAXED, __HIP_MEMORY_SCOPE_AGENT);
                }
            }
        }
        while (__hip_atomic_load(genp, __ATOMIC_RELAXED, __HIP_MEMORY_SCOPE_AGENT) == g)
            __builtin_amdgcn_s_sleep(16);
    }
    __syncthreads();
}

// ---------------- persistent routing kernel v3 ----------------
__global__ __launch_bounds__(256, 2) void mega(const float* __restrict__ xT,
                                               const float* __restrict__ W,
                                               float* __restrict__ sp,
                                               float* __restrict__ vbuf,
                                               float* __restrict__ bij,
                                               float* __restrict__ out,
                                               unsigned* __restrict__ bar) {
    __shared__ float4 ws[CCH * NU * 2 * 16];            // 46080 B raw W [cc][d][h][uq]
    __shared__ __align__(16) float xs[CCH * BT * IU];   // 18432 B  [cc][bl][i]
    __shared__ float aux[NU * US];                      // 640 B (squash smag)
    __shared__ float cs[NU * CCH];                      // 360 B (c_ij slice)

    const int tid = threadIdx.x;
    const int bid = blockIdx.x;
    const int grp = bid & 7;
    const int slot = bid >> 3;
    const int ch = ((slot >> 2) << 3) | grp;   // chunk pinned to one XCD (perf-only)
    const int bt = slot & 3;
    const int b0 = bt * BT, c0 = ch * CCH;

    // ---- one-time staging (plain cached loads: read-only inputs) ----
    const float4* wg = (const float4*)W + (size_t)c0 * 320;
    for (int q = tid; q < CCH * NU * 32; q += 256) {
        int h = q & 1, u = (q >> 1) & 15, cd = q >> 5;
        ws[(cd * 2 + h) * 16 + u] = wg[q];
    }
    const float4* xg = (const float4*)xT;
    float4* xsv = (float4*)xs;
    for (int q = tid; q < CCH * BT * 2; q += 256) {
        int cc = q >> 7, r = q & 127;
        xsv[cc * 128 + r] = xg[(size_t)(c0 + cc) * (ROWS / 4) + b0 * 2 + r];
    }

    const int uq = tid & 15;
    const int bs = tid >> 4;
    const int wv = tid >> 6;      // wave id 0..3
    const int lane = tid & 63;

    for (int iter = 0; iter < 3; ++iter) {
        // ---- c_ij slice: uniform (iter 0) or per-block softmax of b_ij rows ----
        __syncthreads();
        if (iter == 0) {
            for (int q = tid; q < NU * CCH; q += 256) cs[q] = 1.0f;
        } else {
            for (int d = wv; d < NU; d += 4) {
                const float* brow = bij + (size_t)d * IC;
                float bv[18];
                float mx = -1e30f;
#pragma unroll
                for (int j = 0; j < 18; j++) {
                    bv[j] = gld(brow + lane + j * 64);
                    mx = fmaxf(mx, bv[j]);
                }
#pragma unroll
                for (int off = 32; off > 0; off >>= 1)
                    mx = fmaxf(mx, __shfl_xor(mx, off, 64));
                float sume = 0.0f;
#pragma unroll
                for (int j = 0; j < 18; j++) sume += expf(bv[j] - mx);
#pragma unroll
                for (int off = 32; off > 0; off >>= 1)
                    sume += __shfl_xor(sume, off, 64);
                const float inv = 1.0f / sume;
                if (lane < CCH)
                    cs[d * CCH + lane] = expf(gld(brow + c0 + lane) - mx) * inv;
            }
        }
        __syncthreads();
        const float scale = iter ? 1.0f : (1.0f / (float)IC);   // softmax(0) uniform

        // ---- s phase ----
        {
            float acc[4][NU];
#pragma unroll
            for (int bb = 0; bb < 4; bb++)
#pragma unroll
                for (int d = 0; d < NU; d++) acc[bb][d] = 0.0f;

#pragma unroll 3
            for (int cc = 0; cc < CCH; cc++) {
                float4 xv0[4], xv1[4];
#pragma unroll
                for (int bb = 0; bb < 4; bb++) {
                    const float4* xp = (const float4*)(xs + (cc * BT + bs + 16 * bb) * IU);
                    xv0[bb] = xp[0]; xv1[bb] = xp[1];
                }
#pragma unroll
                for (int d = 0; d < NU; d++) {
                    float4 w0 = ws[((cc * NU + d) * 2 + 0) * 16 + uq];
                    float4 w1 = ws[((cc * NU + d) * 2 + 1) * 16 + uq];
                    const float cw = cs[d * CCH + cc];
#pragma unroll
                    for (int bb = 0; bb < 4; bb++) {
                        float uh = w0.x * xv0[bb].x + w0.y * xv0[bb].y + w0.z * xv0[bb].z + w0.w * xv0[bb].w
                                 + w1.x * xv1[bb].x + w1.y * xv1[bb].y + w1.z * xv1[bb].z + w1.w * xv1[bb].w;
                        acc[bb][d] = fmaf(cw, uh, acc[bb][d]);
                    }
                }
            }
#pragma unroll
            for (int bb = 0; bb < 4; bb++) {
                const int b = b0 + bs + 16 * bb;
#pragma unroll
                for (int d = 0; d < NU; d++)
                    gst(sp + (((size_t)ch * B_ + b) * NU + d) * US + uq, acc[bb][d] * scale);
            }
        }
        gridbar(bar);

        // ---- squash: blocks 0..255, one batch each ----
        if (bid < B_) {
            float s = 0.0f;
            if (tid < NU * US) {
#pragma unroll 16
                for (int chp = 0; chp < NCH; chp++)
                    s += gld(sp + ((size_t)chp * B_ + bid) * (NU * US) + tid);
                aux[tid] = s * s;
            }
            __syncthreads();
            if (tid < NU * US) {
                float msq = 0.0f;
#pragma unroll
                for (int dd = 0; dd < NU; dd++) msq += aux[dd * US + uq];
                float f = msq / ((1.0f + msq) * sqrtf(msq));
                if (iter == 2)
                    out[(size_t)bid * (NU * US) + tid] = s * f;   // plain: kernel-end flush
                else
                    gst(vbuf + (size_t)bid * (NU * US) + tid, s * f);
            }
        }
        if (iter == 2) return;
        gridbar(bar);

        // ---- agree phase: thread (uq, cl<9); W from LDS regs, 64 b streamed;
        //      partials atomically accumulated into b_ij logits ----
        {
            const int cl = tid >> 4;
            if (cl < CCH) {
                float4 wA[NU], wB[NU];
#pragma unroll
                for (int d = 0; d < NU; d++) {
                    wA[d] = ws[((cl * NU + d) * 2 + 0) * 16 + uq];
                    wB[d] = ws[((cl * NU + d) * 2 + 1) * 16 + uq];
                }
                float accd[NU];
#pragma unroll
                for (int d = 0; d < NU; d++) accd[d] = 0.0f;
                const int bstag = (cl & 3) * 7;   // de-conflict x-reads across cl
#pragma unroll 4
                for (int blx = 0; blx < BT; blx++) {
                    const int bl = (blx + bstag) & 63;
                    const float* xp = xs + (cl * BT + bl) * IU;
                    float4 x0 = *(const float4*)xp;
                    float4 x1 = *(const float4*)(xp + 4);
                    const float* vp = vbuf + (size_t)(b0 + bl) * (NU * US) + uq;
#pragma unroll
                    for (int d = 0; d < NU; d++) {
                        float uh = wA[d].x * x0.x + wA[d].y * x0.y + wA[d].z * x0.z + wA[d].w * x0.w
                                 + wB[d].x * x1.x + wB[d].y * x1.y + wB[d].z * x1.z + wB[d].w * x1.w;
                        accd[d] = fmaf(uh, gld(vp + d * US), accd[d]);
                    }
                }
#pragma unroll
                for (int d = 0; d < NU; d++) {
                    float a = accd[d];
                    a += __shfl_xor(a, 1, 64);
                    a += __shfl_xor(a, 2, 64);
                    a += __shfl_xor(a, 4, 64);
                    a += __shfl_xor(a, 8, 64);
                    if (uq == 0)
                        atomicAdd(bij + (size_t)d * IC + c0 + cl, a * (1.0f / (float)B_));
                }
            }
        }
        gridbar(bar);
    }
}

extern "C" void kernel_launch(void* const* d_in, const int* in_sizes, int n_in,
                              void* d_out, int out_size, void* d_ws, size_t ws_size,
                              hipStream_t stream) {
    (void)in_sizes; (void)n_in; (void)out_size; (void)ws_size;
    const float* x = (const float*)d_in[0];   // [256, 8, 1152]
    const float* W = (const float*)d_in[1];   // [1, 1152, 10, 16, 8]
    float* out = (float*)d_out;               // [256, 10, 16] fp32

    // workspace: bar (3072 u32) | bij (11520 f, zeroed) | xT | sp | vbuf  (~30 MiB)
    unsigned* bar = (unsigned*)d_ws;
    float* bij = (float*)d_ws + 3072;
    float* xT  = bij + (size_t)NU * IC;
    float* sp  = xT + (size_t)IC * ROWS;
    float* vbuf = sp + (size_t)NCH * B_ * NU * US;

    hipMemsetAsync(d_ws, 0, 3072 * 4 + (size_t)NU * IC * 4, stream);  // bar + bij
    transpose_x<<<36 * 64, 256, 0, stream>>>(x, xT);
    mega<<<NBLK, 256, 0, stream>>>(xT, W, sp, vbuf, bij, out, bar);
}

// Round 8
// 204.829 us; speedup vs baseline: 2.3975x; 1.3430x over previous
//
#include <hip/hip_runtime.h>
#include <math.h>

#define B_  256
#define IU  8
#define IC  1152
#define NU  10
#define US  16
#define ROWS 2048   // B_*IU
#define CCH 9
#define NCH 128
#define BT  64
#define NBLK 512

// scalar cache-bypassing accessors (coherence point = L3). Used ONLY for buffers
// rewritten+re-read within one launch (sp, bij) and cross-XCD producer writes.
__device__ __forceinline__ float gld(const float* p) {
    return __hip_atomic_load(p, __ATOMIC_RELAXED, __HIP_MEMORY_SCOPE_AGENT);
}
__device__ __forceinline__ void gst(float* p, float v) {
    __hip_atomic_store(p, v, __ATOMIC_RELAXED, __HIP_MEMORY_SCOPE_AGENT);
}
__device__ __forceinline__ unsigned uld(const unsigned* p) {
    return __hip_atomic_load(p, __ATOMIC_RELAXED, __HIP_MEMORY_SCOPE_AGENT);
}
__device__ __forceinline__ void ust(unsigned* p, unsigned v) {
    __hip_atomic_store(p, v, __ATOMIC_RELAXED, __HIP_MEMORY_SCOPE_AGENT);
}

// ---------------- x transpose: x[b][i][c] -> xT[c][b*8+i] ----------------
__global__ __launch_bounds__(256) void transpose_x(const float* __restrict__ x,
                                                   float* __restrict__ xT) {
    __shared__ float t[32][33];
    const int tx = threadIdx.x & 31, ty = threadIdx.x >> 5;
    const int ct = blockIdx.x % 36;
    const int rt = blockIdx.x / 36;
    const int c0 = ct * 32, r0 = rt * 32;
#pragma unroll
    for (int k = 0; k < 32; k += 8)
        t[ty + k][tx] = x[(size_t)(r0 + ty + k) * IC + c0 + tx];
    __syncthreads();
#pragma unroll
    for (int k = 0; k < 32; k += 8)
        xT[(size_t)(c0 + ty + k) * ROWS + r0 + tx] = t[tx][ty + k];
}

// ---------------- fence-free grid barrier, HIERARCHICAL RELEASE ----------------
// Arrival: 3-level tree 8x8x8 on padded (128B) cachelines.
// Release: top releaser writes 8 mid-release lines R2[h] (1 poller each);
// each mid-last-arriver then writes its 8 leaf-release lines R1[l] (8 pollers
// each). Max pollers per line = 8 (was 64) -> no L3 same-line queueing.
// Line map (x32 u32): leafcnt[l]=l (l<64) | midcnt[h]=64+h | topcnt=72
//                     R2[h]=80+h | R1[l]=96+l.  Total 160 lines = 20480 B.
__device__ __forceinline__ void gridbar(unsigned* bar) {
    __syncthreads();
    if (threadIdx.x == 0) {
        const int bid = blockIdx.x;
        const int leaf = bid >> 3;        // 0..63
        const int mid  = bid >> 6;        // 0..7
        unsigned* myR1 = bar + (96 + leaf) * 32;
        unsigned g = uld(myR1);
        unsigned a = __hip_atomic_fetch_add(bar + leaf * 32, 1u,
                                            __ATOMIC_RELAXED, __HIP_MEMORY_SCOPE_AGENT);
        if (a == 7u) {
            ust(bar + leaf * 32, 0u);
            unsigned b2 = __hip_atomic_fetch_add(bar + (64 + mid) * 32, 1u,
                                                 __ATOMIC_RELAXED, __HIP_MEMORY_SCOPE_AGENT);
            if (b2 == 7u) {
                ust(bar + (64 + mid) * 32, 0u);
                unsigned c2 = __hip_atomic_fetch_add(bar + 72 * 32, 1u,
                                                     __ATOMIC_RELAXED, __HIP_MEMORY_SCOPE_AGENT);
                if (c2 == 7u) {
                    ust(bar + 72 * 32, 0u);
#pragma unroll
                    for (int k = 0; k < 8; k++)
                        ust(bar + (80 + k) * 32, g + 1u);
                }
                // mid-last-arriver (incl. top releaser): await R2, fan out to leaves
                while (uld(bar + (80 + mid) * 32) == g)
                    __builtin_amdgcn_s_sleep(8);
#pragma unroll
                for (int j = 0; j < 8; j++)
                    ust(bar + (96 + mid * 8 + j) * 32, g + 1u);
            }
        }
        while (uld(myR1) == g)
            __builtin_amdgcn_s_sleep(16);
    }
    __syncthreads();
}

// ---------------- persistent routing kernel v6 ----------------
// Block = (c-chunk of 9 channels, b-tile of 64). W+x staged in LDS once, reused by
// 3 s-phases + 2 agree-phases. 7 grid barriers. vb0/vb1 double-buffered so agree
// reads v through the normal cached path (write-once-read-once per launch).
__global__ __launch_bounds__(256, 2) void mega(const float* __restrict__ xT,
                                               const float* __restrict__ W,
                                               float* __restrict__ sp,
                                               float* __restrict__ vb0,
                                               float* __restrict__ vb1,
                                               float* __restrict__ bij,
                                               float* __restrict__ out,
                                               unsigned* __restrict__ bar) {
    __shared__ float4 ws[CCH * NU * 2 * 16];            // 46080 B raw W [cc][d][h][uq]
    __shared__ __align__(16) float xs[CCH * BT * IU];   // 18432 B  [cc][bl][i]
    __shared__ float aux[NU * US];                      // 640 B (squash smag)
    __shared__ float cs[NU * CCH];                      // 360 B (c_ij slice)

    const int tid = threadIdx.x;
    const int bid = blockIdx.x;
    const int grp = bid & 7;
    const int slot_ = bid >> 3;
    const int ch = ((slot_ >> 2) << 3) | grp;   // chunk pinned to one XCD (perf-only)
    const int bt = slot_ & 3;
    const int b0 = bt * BT, c0 = ch * CCH;

    // ---- one-time staging (plain cached loads: read-only inputs) ----
    const float4* wg = (const float4*)W + (size_t)c0 * 320;
    for (int q = tid; q < CCH * NU * 32; q += 256) {
        int h = q & 1, u = (q >> 1) & 15, cd = q >> 5;
        ws[(cd * 2 + h) * 16 + u] = wg[q];
    }
    const float4* xg = (const float4*)xT;
    float4* xsv = (float4*)xs;
    for (int q = tid; q < CCH * BT * 2; q += 256) {
        int cc = q >> 7, r = q & 127;
        xsv[cc * 128 + r] = xg[(size_t)(c0 + cc) * (ROWS / 4) + b0 * 2 + r];
    }

    const int uq = tid & 15;
    const int bs = tid >> 4;
    const int wv = tid >> 6;      // wave id 0..3
    const int lane = tid & 63;

    for (int iter = 0; iter < 3; ++iter) {
        // ---- c_ij slice: uniform (iter 0) or per-block softmax of b_ij rows ----
        __syncthreads();
        if (iter == 0) {
            for (int q = tid; q < NU * CCH; q += 256) cs[q] = 1.0f;
        } else {
            for (int d = wv; d < NU; d += 4) {
                const float* brow = bij + (size_t)d * IC;
                float bv[18];
                float mx = -1e30f;
#pragma unroll
                for (int j = 0; j < 18; j++) {
                    bv[j] = gld(brow + lane + j * 64);
                    mx = fmaxf(mx, bv[j]);
                }
#pragma unroll
                for (int off = 32; off > 0; off >>= 1)
                    mx = fmaxf(mx, __shfl_xor(mx, off, 64));
                float sume = 0.0f;
#pragma unroll
                for (int j = 0; j < 18; j++) sume += expf(bv[j] - mx);
#pragma unroll
                for (int off = 32; off > 0; off >>= 1)
                    sume += __shfl_xor(sume, off, 64);
                const float inv = 1.0f / sume;
                if (lane < CCH)
                    cs[d * CCH + lane] = expf(gld(brow + c0 + lane) - mx) * inv;
            }
        }
        __syncthreads();
        const float scale = iter ? 1.0f : (1.0f / (float)IC);   // softmax(0) uniform

        // ---- s phase ----
        {
            float acc[4][NU];
#pragma unroll
            for (int bb = 0; bb < 4; bb++)
#pragma unroll
                for (int d = 0; d < NU; d++) acc[bb][d] = 0.0f;

#pragma unroll 3
            for (int cc = 0; cc < CCH; cc++) {
                float4 xv0[4], xv1[4];
#pragma unroll
                for (int bb = 0; bb < 4; bb++) {
                    const float4* xp = (const float4*)(xs + (cc * BT + bs + 16 * bb) * IU);
                    xv0[bb] = xp[0]; xv1[bb] = xp[1];
                }
#pragma unroll
                for (int d = 0; d < NU; d++) {
                    float4 w0 = ws[((cc * NU + d) * 2 + 0) * 16 + uq];
                    float4 w1 = ws[((cc * NU + d) * 2 + 1) * 16 + uq];
                    const float cw = cs[d * CCH + cc];
#pragma unroll
                    for (int bb = 0; bb < 4; bb++) {
                        float uh = w0.x * xv0[bb].x + w0.y * xv0[bb].y + w0.z * xv0[bb].z + w0.w * xv0[bb].w
                                 + w1.x * xv1[bb].x + w1.y * xv1[bb].y + w1.z * xv1[bb].z + w1.w * xv1[bb].w;
                        acc[bb][d] = fmaf(cw, uh, acc[bb][d]);
                    }
                }
            }
#pragma unroll
            for (int bb = 0; bb < 4; bb++) {
                const int b = b0 + bs + 16 * bb;
#pragma unroll
                for (int d = 0; d < NU; d++)
                    gst(sp + (((size_t)ch * B_ + b) * NU + d) * US + uq, acc[bb][d] * scale);
            }
        }
        gridbar(bar);

        // ---- squash: blocks 0..255, one batch each; sp is rewritten each
        //      iteration -> must stay L3-direct (gld) ----
        if (bid < B_) {
            float s = 0.0f;
            if (tid < NU * US) {
#pragma unroll 16
                for (int chp = 0; chp < NCH; chp++)
                    s += gld(sp + ((size_t)chp * B_ + bid) * (NU * US) + tid);
                aux[tid] = s * s;
            }
            __syncthreads();
            if (tid < NU * US) {
                float msq = 0.0f;
#pragma unroll
                for (int dd = 0; dd < NU; dd++) msq += aux[dd * US + uq];
                float f = msq / ((1.0f + msq) * sqrtf(msq));
                if (iter == 2)
                    out[(size_t)bid * (NU * US) + tid] = s * f;   // kernel-end flush
                else {
                    float* vdst = (iter == 0) ? vb0 : vb1;
                    gst(vdst + (size_t)bid * (NU * US) + tid, s * f);
                }
            }
        }
        if (iter == 2) return;
        gridbar(bar);

        // ---- agree phase: thread (uq, cl<9); W from LDS regs, 64 b streamed.
        //      vb is write-once-read-once per launch -> PLAIN CACHED loads
        //      (dispatch-boundary invalidation makes this safe; proven by the
        //      split-kernel rounds which read prior-kernel data plainly). ----
        {
            const int cl = tid >> 4;
            const float* vb = (iter == 0) ? vb0 : vb1;
            if (cl < CCH) {
                float4 wA[NU], wB[NU];
#pragma unroll
                for (int d = 0; d < NU; d++) {
                    wA[d] = ws[((cl * NU + d) * 2 + 0) * 16 + uq];
                    wB[d] = ws[((cl * NU + d) * 2 + 1) * 16 + uq];
                }
                float accd[NU];
#pragma unroll
                for (int d = 0; d < NU; d++) accd[d] = 0.0f;
                const int bstag = (cl & 3) * 7;   // de-conflict xs reads across cl
#pragma unroll 4
                for (int blx = 0; blx < BT; blx++) {
                    const int bl = (blx + bstag) & 63;
                    const float* xp = xs + (cl * BT + bl) * IU;
                    float4 x0 = *(const float4*)xp;
                    float4 x1 = *(const float4*)(xp + 4);
                    const float* vp = vb + (size_t)(b0 + bl) * (NU * US) + uq;
#pragma unroll
                    for (int d = 0; d < NU; d++) {
                        float uh = wA[d].x * x0.x + wA[d].y * x0.y + wA[d].z * x0.z + wA[d].w * x0.w
                                 + wB[d].x * x1.x + wB[d].y * x1.y + wB[d].z * x1.z + wB[d].w * x1.w;
                        accd[d] = fmaf(uh, vp[d * US], accd[d]);
                    }
                }
#pragma unroll
                for (int d = 0; d < NU; d++) {
                    float a = accd[d];
                    a += __shfl_xor(a, 1, 64);
                    a += __shfl_xor(a, 2, 64);
                    a += __shfl_xor(a, 4, 64);
                    a += __shfl_xor(a, 8, 64);
                    if (uq == 0)
                        atomicAdd(bij + (size_t)d * IC + c0 + cl, a * (1.0f / (float)B_));
                }
            }
        }
        gridbar(bar);
    }
}

extern "C" void kernel_launch(void* const* d_in, const int* in_sizes, int n_in,
                              void* d_out, int out_size, void* d_ws, size_t ws_size,
                              hipStream_t stream) {
    (void)in_sizes; (void)n_in; (void)out_size; (void)ws_size;
    const float* x = (const float*)d_in[0];   // [256, 8, 1152]
    const float* W = (const float*)d_in[1];   // [1, 1152, 10, 16, 8]
    float* out = (float*)d_out;               // [256, 10, 16] fp32

    // workspace: bar (5120 u32 = 20 KB) | bij | xT | sp | vb0 | vb1  (~31 MiB)
    unsigned* bar = (unsigned*)d_ws;
    float* bij = (float*)d_ws + 5120;
    float* xT  = bij + (size_t)NU * IC;
    float* sp  = xT + (size_t)IC * ROWS;
    float* vb0 = sp + (size_t)NCH * B_ * NU * US;
    float* vb1 = vb0 + (size_t)B_ * NU * US;

    hipMemsetAsync(d_ws, 0, 5120 * 4 + (size_t)NU * IC * 4, stream);  // bar + bij
    transpose_x<<<36 * 64, 256, 0, stream>>>(x, xT);
    mega<<<NBLK, 256, 0, stream>>>(xT, W, sp, vb0, vb1, bij, out, bar);
}

// Round 9
// 194.896 us; speedup vs baseline: 2.5197x; 1.0510x over previous
//
#include <hip/hip_runtime.h>
#include <math.h>

#define B_  256
#define IU  8
#define IC  1152
#define NU  10
#define US  16
#define ROWS 2048   // B_*IU
#define CCH 9
#define NCH 128
#define BT  64
#define NBLK 512
#define SPSTRIDE ((size_t)NCH * B_ * NU * US)   // floats per sp buffer

// scalar cache-bypassing accessors (coherence point). Used ONLY for producer
// writes that must be cross-XCD visible (sp, vb) and small rewritten data (bij).
__device__ __forceinline__ float gld(const float* p) {
    return __hip_atomic_load(p, __ATOMIC_RELAXED, __HIP_MEMORY_SCOPE_AGENT);
}
__device__ __forceinline__ void gst(float* p, float v) {
    __hip_atomic_store(p, v, __ATOMIC_RELAXED, __HIP_MEMORY_SCOPE_AGENT);
}
__device__ __forceinline__ unsigned uld(const unsigned* p) {
    return __hip_atomic_load(p, __ATOMIC_RELAXED, __HIP_MEMORY_SCOPE_AGENT);
}
__device__ __forceinline__ void ust(unsigned* p, unsigned v) {
    __hip_atomic_store(p, v, __ATOMIC_RELAXED, __HIP_MEMORY_SCOPE_AGENT);
}

// ---------------- x transpose: x[b][i][c] -> xT[c][b*8+i] ----------------
__global__ __launch_bounds__(256) void transpose_x(const float* __restrict__ x,
                                                   float* __restrict__ xT) {
    __shared__ float t[32][33];
    const int tx = threadIdx.x & 31, ty = threadIdx.x >> 5;
    const int ct = blockIdx.x % 36;
    const int rt = blockIdx.x / 36;
    const int c0 = ct * 32, r0 = rt * 32;
#pragma unroll
    for (int k = 0; k < 32; k += 8)
        t[ty + k][tx] = x[(size_t)(r0 + ty + k) * IC + c0 + tx];
    __syncthreads();
#pragma unroll
    for (int k = 0; k < 32; k += 8)
        xT[(size_t)(c0 + ty + k) * ROWS + r0 + tx] = t[tx][ty + k];
}

// ---------------- fence-free grid barrier, hierarchical release (R8, proven) --
__device__ __forceinline__ void gridbar(unsigned* bar) {
    __syncthreads();
    if (threadIdx.x == 0) {
        const int bid = blockIdx.x;
        const int leaf = bid >> 3;        // 0..63
        const int mid  = bid >> 6;        // 0..7
        unsigned* myR1 = bar + (96 + leaf) * 32;
        unsigned g = uld(myR1);
        unsigned a = __hip_atomic_fetch_add(bar + leaf * 32, 1u,
                                            __ATOMIC_RELAXED, __HIP_MEMORY_SCOPE_AGENT);
        if (a == 7u) {
            ust(bar + leaf * 32, 0u);
            unsigned b2 = __hip_atomic_fetch_add(bar + (64 + mid) * 32, 1u,
                                                 __ATOMIC_RELAXED, __HIP_MEMORY_SCOPE_AGENT);
            if (b2 == 7u) {
                ust(bar + (64 + mid) * 32, 0u);
                unsigned c2 = __hip_atomic_fetch_add(bar + 72 * 32, 1u,
                                                     __ATOMIC_RELAXED, __HIP_MEMORY_SCOPE_AGENT);
                if (c2 == 7u) {
                    ust(bar + 72 * 32, 0u);
#pragma unroll
                    for (int k = 0; k < 8; k++)
                        ust(bar + (80 + k) * 32, g + 1u);
                }
                while (uld(bar + (80 + mid) * 32) == g)
                    __builtin_amdgcn_s_sleep(8);
#pragma unroll
                for (int j = 0; j < 8; j++)
                    ust(bar + (96 + mid * 8 + j) * 32, g + 1u);
            }
        }
        while (uld(myR1) == g)
            __builtin_amdgcn_s_sleep(16);
    }
    __syncthreads();
}

// ---------------- persistent routing kernel v7 ----------------
// Change vs R8: sp triple-buffered (one buffer per iteration) so squash reads
// take the normal CACHED path as float4 (write-once-read-once per launch;
// kernel-entry acquire kills stale lines from prior graph replays).
__global__ __launch_bounds__(256, 2) void mega(const float* __restrict__ xT,
                                               const float* __restrict__ W,
                                               float* __restrict__ sp,     // 3 buffers
                                               float* __restrict__ vb0,
                                               float* __restrict__ vb1,
                                               float* __restrict__ bij,
                                               float* __restrict__ out,
                                               unsigned* __restrict__ bar) {
    __shared__ float4 ws[CCH * NU * 2 * 16];            // 46080 B raw W [cc][d][h][uq]
    __shared__ __align__(16) float xs[CCH * BT * IU];   // 18432 B  [cc][bl][i]
    __shared__ float aux[NU * US];                      // 640 B (squash s-vector)
    __shared__ float cs[NU * CCH];                      // 360 B (c_ij slice)

    const int tid = threadIdx.x;
    const int bid = blockIdx.x;
    const int grp = bid & 7;
    const int slot_ = bid >> 3;
    const int ch = ((slot_ >> 2) << 3) | grp;   // chunk pinned to one XCD (perf-only)
    const int bt = slot_ & 3;
    const int b0 = bt * BT, c0 = ch * CCH;

    // ---- one-time staging (plain cached loads: read-only inputs) ----
    const float4* wg = (const float4*)W + (size_t)c0 * 320;
    for (int q = tid; q < CCH * NU * 32; q += 256) {
        int h = q & 1, u = (q >> 1) & 15, cd = q >> 5;
        ws[(cd * 2 + h) * 16 + u] = wg[q];
    }
    const float4* xg = (const float4*)xT;
    float4* xsv = (float4*)xs;
    for (int q = tid; q < CCH * BT * 2; q += 256) {
        int cc = q >> 7, r = q & 127;
        xsv[cc * 128 + r] = xg[(size_t)(c0 + cc) * (ROWS / 4) + b0 * 2 + r];
    }

    const int uq = tid & 15;
    const int bs = tid >> 4;
    const int wv = tid >> 6;      // wave id 0..3
    const int lane = tid & 63;

    for (int iter = 0; iter < 3; ++iter) {
        float* spb = sp + (size_t)iter * SPSTRIDE;   // this iteration's buffer

        // ---- c_ij slice: uniform (iter 0) or per-block softmax of b_ij rows ----
        __syncthreads();
        if (iter == 0) {
            for (int q = tid; q < NU * CCH; q += 256) cs[q] = 1.0f;
        } else {
            for (int d = wv; d < NU; d += 4) {
                const float* brow = bij + (size_t)d * IC;
                float bv[18];
                float mx = -1e30f;
#pragma unroll
                for (int j = 0; j < 18; j++) {
                    bv[j] = gld(brow + lane + j * 64);
                    mx = fmaxf(mx, bv[j]);
                }
#pragma unroll
                for (int off = 32; off > 0; off >>= 1)
                    mx = fmaxf(mx, __shfl_xor(mx, off, 64));
                float sume = 0.0f;
#pragma unroll
                for (int j = 0; j < 18; j++) sume += expf(bv[j] - mx);
#pragma unroll
                for (int off = 32; off > 0; off >>= 1)
                    sume += __shfl_xor(sume, off, 64);
                const float inv = 1.0f / sume;
                if (lane < CCH)
                    cs[d * CCH + lane] = expf(gld(brow + c0 + lane) - mx) * inv;
            }
        }
        __syncthreads();
        const float scale = iter ? 1.0f : (1.0f / (float)IC);   // softmax(0) uniform

        // ---- s phase ----
        {
            float acc[4][NU];
#pragma unroll
            for (int bb = 0; bb < 4; bb++)
#pragma unroll
                for (int d = 0; d < NU; d++) acc[bb][d] = 0.0f;

#pragma unroll 3
            for (int cc = 0; cc < CCH; cc++) {
                float4 xv0[4], xv1[4];
#pragma unroll
                for (int bb = 0; bb < 4; bb++) {
                    const float4* xp = (const float4*)(xs + (cc * BT + bs + 16 * bb) * IU);
                    xv0[bb] = xp[0]; xv1[bb] = xp[1];
                }
#pragma unroll
                for (int d = 0; d < NU; d++) {
                    float4 w0 = ws[((cc * NU + d) * 2 + 0) * 16 + uq];
                    float4 w1 = ws[((cc * NU + d) * 2 + 1) * 16 + uq];
                    const float cw = cs[d * CCH + cc];
#pragma unroll
                    for (int bb = 0; bb < 4; bb++) {
                        float uh = w0.x * xv0[bb].x + w0.y * xv0[bb].y + w0.z * xv0[bb].z + w0.w * xv0[bb].w
                                 + w1.x * xv1[bb].x + w1.y * xv1[bb].y + w1.z * xv1[bb].z + w1.w * xv1[bb].w;
                        acc[bb][d] = fmaf(cw, uh, acc[bb][d]);
                    }
                }
            }
#pragma unroll
            for (int bb = 0; bb < 4; bb++) {
                const int b = b0 + bs + 16 * bb;
#pragma unroll
                for (int d = 0; d < NU; d++)
                    gst(spb + (((size_t)ch * B_ + b) * NU + d) * US + uq, acc[bb][d] * scale);
            }
        }
        gridbar(bar);

        // ---- squash: blocks 0..255, one batch each. spb is write-once-read-once
        //      per launch -> PLAIN CACHED float4 loads; part-combine via shfl. ----
        if (bid < B_) {
            if (tid < 160) {
                const int part = tid & 3;     // 4 chunk-quarters in adjacent lanes
                const int sl = tid >> 2;      // float4 slot 0..39 of the 160-vec
                const float4* s4p = (const float4*)spb;
                float4 a = make_float4(0.f, 0.f, 0.f, 0.f);
#pragma unroll 8
                for (int k = 0; k < 32; ++k) {
                    float4 t = s4p[((size_t)(part * 32 + k) * B_ + bid) * 40 + sl];
                    a.x += t.x; a.y += t.y; a.z += t.z; a.w += t.w;
                }
                // combine the 4 parts (adjacent lanes) via xor-shuffles
                a.x += __shfl_xor(a.x, 1, 64); a.y += __shfl_xor(a.y, 1, 64);
                a.z += __shfl_xor(a.z, 1, 64); a.w += __shfl_xor(a.w, 1, 64);
                a.x += __shfl_xor(a.x, 2, 64); a.y += __shfl_xor(a.y, 2, 64);
                a.z += __shfl_xor(a.z, 2, 64); a.w += __shfl_xor(a.w, 2, 64);
                if (part == 0) {
                    aux[sl * 4 + 0] = a.x; aux[sl * 4 + 1] = a.y;
                    aux[sl * 4 + 2] = a.z; aux[sl * 4 + 3] = a.w;
                }
            }
            __syncthreads();
            if (tid < NU * US) {
                float s = aux[tid];
                float msq = 0.0f;
#pragma unroll
                for (int dd = 0; dd < NU; dd++) {
                    float t = aux[dd * US + uq];
                    msq = fmaf(t, t, msq);
                }
                float f = msq / ((1.0f + msq) * sqrtf(msq));
                if (iter == 2)
                    out[(size_t)bid * (NU * US) + tid] = s * f;   // kernel-end flush
                else {
                    float* vdst = (iter == 0) ? vb0 : vb1;
                    gst(vdst + (size_t)bid * (NU * US) + tid, s * f);
                }
            }
        }
        if (iter == 2) return;
        gridbar(bar);

        // ---- agree phase: thread (uq, cl<9); W from LDS regs, 64 b streamed.
        //      vb is write-once-read-once per launch -> PLAIN CACHED loads. ----
        {
            const int cl = tid >> 4;
            const float* vb = (iter == 0) ? vb0 : vb1;
            if (cl < CCH) {
                float4 wA[NU], wB[NU];
#pragma unroll
                for (int d = 0; d < NU; d++) {
                    wA[d] = ws[((cl * NU + d) * 2 + 0) * 16 + uq];
                    wB[d] = ws[((cl * NU + d) * 2 + 1) * 16 + uq];
                }
                float accd[NU];
#pragma unroll
                for (int d = 0; d < NU; d++) accd[d] = 0.0f;
                const int bstag = (cl & 3) * 7;   // de-conflict xs reads across cl
#pragma unroll 4
                for (int blx = 0; blx < BT; blx++) {
                    const int bl = (blx + bstag) & 63;
                    const float* xp = xs + (cl * BT + bl) * IU;
                    float4 x0 = *(const float4*)xp;
                    float4 x1 = *(const float4*)(xp + 4);
                    const float* vp = vb + (size_t)(b0 + bl) * (NU * US) + uq;
#pragma unroll
                    for (int d = 0; d < NU; d++) {
                        float uh = wA[d].x * x0.x + wA[d].y * x0.y + wA[d].z * x0.z + wA[d].w * x0.w
                                 + wB[d].x * x1.x + wB[d].y * x1.y + wB[d].z * x1.z + wB[d].w * x1.w;
                        accd[d] = fmaf(uh, vp[d * US], accd[d]);
                    }
                }
#pragma unroll
                for (int d = 0; d < NU; d++) {
                    float a = accd[d];
                    a += __shfl_xor(a, 1, 64);
                    a += __shfl_xor(a, 2, 64);
                    a += __shfl_xor(a, 4, 64);
                    a += __shfl_xor(a, 8, 64);
                    if (uq == 0)
                        atomicAdd(bij + (size_t)d * IC + c0 + cl, a * (1.0f / (float)B_));
                }
            }
        }
        gridbar(bar);
    }
}

extern "C" void kernel_launch(void* const* d_in, const int* in_sizes, int n_in,
                              void* d_out, int out_size, void* d_ws, size_t ws_size,
                              hipStream_t stream) {
    (void)in_sizes; (void)n_in; (void)out_size; (void)ws_size;
    const float* x = (const float*)d_in[0];   // [256, 8, 1152]
    const float* W = (const float*)d_in[1];   // [1, 1152, 10, 16, 8]
    float* out = (float*)d_out;               // [256, 10, 16] fp32

    // workspace: bar (20 KB) | bij | xT | sp x3 | vb0 | vb1   (~73 MiB)
    unsigned* bar = (unsigned*)d_ws;
    float* bij = (float*)d_ws + 5120;
    float* xT  = bij + (size_t)NU * IC;
    float* sp  = xT + (size_t)IC * ROWS;
    float* vb0 = sp + 3 * SPSTRIDE;
    float* vb1 = vb0 + (size_t)B_ * NU * US;

    hipMemsetAsync(d_ws, 0, 5120 * 4 + (size_t)NU * IC * 4, stream);  // bar + bij
    transpose_x<<<36 * 64, 256, 0, stream>>>(x, xT);
    mega<<<NBLK, 256, 0, stream>>>(xT, W, sp, vb0, vb1, bij, out, bar);
}